// Round 10
// baseline (86.970 us; speedup 1.0000x reference)
//
#include <hip/hip_runtime.h>
#include <hip/hip_bf16.h>

#define LL 128
#define HH 768
#define OFF_REL  0
#define OFF_MASK 131072
#define OFF_HSRC 131840
#define OFF_HTGT 918272
#define SCALEC 2.8853900817779268f   // 2*log2(e):  e^{2x} = exp2(SCALEC*x)

typedef __attribute__((ext_vector_type(8))) short short8;
typedef __attribute__((ext_vector_type(4))) float floatx4;

__device__ __forceinline__ short8 pack8(float4 lo, float4 hi) {
  union { __hip_bfloat162 h2[4]; short8 s8; } u;
  u.h2[0] = __float22bfloat162_rn(float2{lo.x, lo.y});
  u.h2[1] = __float22bfloat162_rn(float2{lo.z, lo.w});
  u.h2[2] = __float22bfloat162_rn(float2{hi.x, hi.y});
  u.h2[3] = __float22bfloat162_rn(float2{hi.z, hi.w});
  return u.s8;
}

// ---------------- hidden fp32 -> bf16 (1.2 MB traffic) ----------------
__global__ __launch_bounds__(256) void cvta_kernel(const float4* __restrict__ hs,
                                                   uint2* __restrict__ ab)
{
  int i = blockIdx.x * 256 + threadIdx.x;   // 49152 float4s
  if (i >= 49152) return;
  float4 v = hs[i];
  union { __hip_bfloat162 h2[2]; uint2 u2; } u;
  u.h2[0] = __float22bfloat162_rn(float2{v.x, v.y});
  u.h2[1] = __float22bfloat162_rn(float2{v.z, v.w});
  ab[i] = u.u2;
}

// ---------------- streaming GEMM: no LDS, no barrier, 3-slot reg pipeline ----------------
// work w in [0,528): strip c = w%264 (32 cols), half = w/264 (128 rows).
// 4 waves/block, each wave an independent 32x32 tile.
__global__ __launch_bounds__(256, 2) void gemm_kernel(
    const unsigned short* __restrict__ Ab,
    const float* __restrict__ Wsrc, const float* __restrict__ Wtgt,
    const float* __restrict__ Wd,
    const float* __restrict__ b_src, const float* __restrict__ b_tgt,
    const float* __restrict__ dense_b,
    float* __restrict__ out, float* __restrict__ z,
    float* __restrict__ Es, float* __restrict__ Et)
{
  int tid = threadIdx.x;
  int wave = tid >> 6, lane = tid & 63;
  int lr = lane & 15, lk8 = (lane >> 4) * 8;

  #pragma unroll 1
  for (int w = blockIdx.x; w < 528; w += 512) {
    int c = w % 264;
    int half = w / 264;
    const float* W; int wrow0; int which;
    if (c < 96)       { W = Wsrc; wrow0 = c * 32;         which = 0; }
    else if (c < 192) { W = Wtgt; wrow0 = (c - 96) * 32;  which = 1; }
    else              { W = Wd;   wrow0 = (c - 192) * 32; which = 2; }

    int rbase = half * 128 + wave * 32;
    const unsigned short* ap0 = Ab + (rbase + lr) * HH + lk8;
    const unsigned short* ap1 = ap0 + 16 * HH;
    const float* wp0 = W + (long)(wrow0 + lr) * HH + lk8;
    const float* wp1 = wp0 + 16 * HH;

    floatx4 acc[2][2];
    #pragma unroll
    for (int mi = 0; mi < 2; ++mi)
      #pragma unroll
      for (int ni = 0; ni < 2; ++ni)
        acc[mi][ni] = (floatx4){0.f, 0.f, 0.f, 0.f};

    short8 a0s[3], a1s[3];
    float4 w0as[3], w0bs[3], w1as[3], w1bs[3];

#define LOADK(K, S) do {                                   \
      a0s[S]  = *(const short8*)(ap0 + (K) * 32);          \
      a1s[S]  = *(const short8*)(ap1 + (K) * 32);          \
      w0as[S] = *(const float4*)(wp0 + (K) * 32);          \
      w0bs[S] = *(const float4*)(wp0 + (K) * 32 + 4);      \
      w1as[S] = *(const float4*)(wp1 + (K) * 32);          \
      w1bs[S] = *(const float4*)(wp1 + (K) * 32 + 4);      \
    } while (0)

    LOADK(0, 0);
    LOADK(1, 1);

    #pragma unroll
    for (int ks = 0; ks < 24; ++ks) {
      const int cur = ks % 3;
      if (ks < 22) {
        const int nxt = (ks + 2) % 3;
        LOADK(ks + 2, nxt);
      }
      short8 b0 = pack8(w0as[cur], w0bs[cur]);
      short8 b1 = pack8(w1as[cur], w1bs[cur]);
      acc[0][0] = __builtin_amdgcn_mfma_f32_16x16x32_bf16(a0s[cur], b0, acc[0][0], 0, 0, 0);
      acc[0][1] = __builtin_amdgcn_mfma_f32_16x16x32_bf16(a0s[cur], b1, acc[0][1], 0, 0, 0);
      acc[1][0] = __builtin_amdgcn_mfma_f32_16x16x32_bf16(a1s[cur], b0, acc[1][0], 0, 0, 0);
      acc[1][1] = __builtin_amdgcn_mfma_f32_16x16x32_bf16(a1s[cur], b1, acc[1][1], 0, 0, 0);
    }
#undef LOADK

    // epilogue
    int lrow = (lane >> 4) * 4;
    #pragma unroll
    for (int mi = 0; mi < 2; ++mi)
    #pragma unroll
    for (int ni = 0; ni < 2; ++ni) {
      int col  = wrow0 + ni * 16 + lr;
      int row0 = rbase + mi * 16 + lrow;
      if (which == 0) {
        float bv = b_src[col];
        #pragma unroll
        for (int r2 = 0; r2 < 4; ++r2) {
          int row = row0 + r2;
          float v = acc[mi][ni][r2] + bv;
          out[OFF_HSRC + row * 3072 + col] = v;
          Es[row * 3072 + col] = __builtin_amdgcn_exp2f(SCALEC * v);
        }
      } else if (which == 1) {
        float bv = b_tgt[col];
        #pragma unroll
        for (int r2 = 0; r2 < 4; ++r2) {
          int row = row0 + r2;
          float v = acc[mi][ni][r2] + bv;
          out[OFF_HTGT + row * 3072 + col] = v;
          Et[row * 3072 + col] = __builtin_amdgcn_exp2f(SCALEC * v);
        }
      } else {
        float bv = dense_b[col];
        #pragma unroll
        for (int r2 = 0; r2 < 4; ++r2)
          z[(row0 + r2) * 2304 + col] = acc[mi][ni][r2] + bv;
      }
    }
  }
}

// ---------------- pairwise relation + token-mask head ----------------
// rel[b,r,s,t] = Wsum - 2*sum_h w[h] / (1 + Es[s,h]*Et[t,h])
#define PHC 256
__global__ __launch_bounds__(512) void pair_kernel(
    const float* __restrict__ Es, const float* __restrict__ Et,
    const float* __restrict__ w_out,
    const float* __restrict__ z, const float* __restrict__ clf_W,
    const float* __restrict__ clf_b, float* __restrict__ out)
{
  int tid = threadIdx.x;

  if (blockIdx.z == 8) {
    // token mask head
    int blk = blockIdx.y * 8 + blockIdx.x;
    int wave = tid >> 6, lane = tid & 63;
    int slot = blk * 8 + wave;
    for (int o = slot; o < 768; o += 512) {
      int b = o / 384, rem = o - b * 384;
      int t = rem >> 7, lt = rem & 127;
      const float* zr = z + (long)(b * LL + lt) * 2304 + t * HH;
      float acc = 0.f;
      for (int h = lane; h < HH; h += 64) {
        float x = zr[h];
        float th = 1.f - 2.f * __builtin_amdgcn_rcpf(1.f + __builtin_amdgcn_exp2f(SCALEC * x));
        acc = fmaf(clf_W[h], th, acc);
      }
      #pragma unroll
      for (int d = 32; d; d >>= 1) acc += __shfl_down(acc, d);
      if (lane == 0) out[OFF_MASK + o] = acc + clf_b[0];
    }
    return;
  }

  __shared__ float sA[16][PHC + 4];
  __shared__ float sB[16][PHC + 4];
  __shared__ float sRed[2048];       // [k][g][p]
  __shared__ float sWsum;

  int g = tid >> 6, lane = tid & 63;
  int sq = lane >> 3, tq = lane & 7;
  int t0 = blockIdx.x * 16, s0 = blockIdx.y * 16;
  int br = blockIdx.z, bb = br >> 2, r = br & 3;

  if (tid < 64) {
    float wsm = 0.f;
    for (int h = tid; h < HH; h += 64) wsm += w_out[h];
    #pragma unroll
    for (int d = 32; d; d >>= 1) wsm += __shfl_down(wsm, d);
    if (tid == 0) sWsum = wsm;
  }

  float a00 = 0.f, a01 = 0.f, a10 = 0.f, a11 = 0.f;

  for (int c = 0; c < HH; c += PHC) {
    int offu = __builtin_amdgcn_readfirstlane(c + g * 32);
    float4 wv[8];
    #pragma unroll
    for (int q = 0; q < 8; ++q) wv[q] = *(const float4*)(w_out + offu + q * 4);

    __syncthreads();
    #pragma unroll
    for (int j = 0; j < 2; ++j) {
      int idx = tid * 2 + j;
      int row = idx >> 6, col4 = (idx & 63) * 4;
      *(float4*)&sA[row][col4] =
          *(const float4*)(Es + (long)(bb * LL + s0 + row) * 3072 + r * HH + c + col4);
      *(float4*)&sB[row][col4] =
          *(const float4*)(Et + (long)(bb * LL + t0 + row) * 3072 + r * HH + c + col4);
    }
    __syncthreads();

    const float* pA0 = &sA[2 * sq][g * 32];
    const float* pA1 = &sA[2 * sq + 1][g * 32];
    const float* pB0 = &sB[2 * tq][g * 32];
    const float* pB1 = &sB[2 * tq + 1][g * 32];
    #pragma unroll
    for (int hh = 0; hh < 32; hh += 4) {
      float4 e0 = *(const float4*)(pA0 + hh);
      float4 e1 = *(const float4*)(pA1 + hh);
      float4 f0 = *(const float4*)(pB0 + hh);
      float4 f1 = *(const float4*)(pB1 + hh);
      float4 vw = wv[hh >> 2];
      a00 = fmaf(vw.x, __builtin_amdgcn_rcpf(fmaf(e0.x, f0.x, 1.f)), a00);
      a01 = fmaf(vw.x, __builtin_amdgcn_rcpf(fmaf(e0.x, f1.x, 1.f)), a01);
      a10 = fmaf(vw.x, __builtin_amdgcn_rcpf(fmaf(e1.x, f0.x, 1.f)), a10);
      a11 = fmaf(vw.x, __builtin_amdgcn_rcpf(fmaf(e1.x, f1.x, 1.f)), a11);
      a00 = fmaf(vw.y, __builtin_amdgcn_rcpf(fmaf(e0.y, f0.y, 1.f)), a00);
      a01 = fmaf(vw.y, __builtin_amdgcn_rcpf(fmaf(e0.y, f1.y, 1.f)), a01);
      a10 = fmaf(vw.y, __builtin_amdgcn_rcpf(fmaf(e1.y, f0.y, 1.f)), a10);
      a11 = fmaf(vw.y, __builtin_amdgcn_rcpf(fmaf(e1.y, f1.y, 1.f)), a11);
      a00 = fmaf(vw.z, __builtin_amdgcn_rcpf(fmaf(e0.z, f0.z, 1.f)), a00);
      a01 = fmaf(vw.z, __builtin_amdgcn_rcpf(fmaf(e0.z, f1.z, 1.f)), a01);
      a10 = fmaf(vw.z, __builtin_amdgcn_rcpf(fmaf(e1.z, f0.z, 1.f)), a10);
      a11 = fmaf(vw.z, __builtin_amdgcn_rcpf(fmaf(e1.z, f1.z, 1.f)), a11);
      a00 = fmaf(vw.w, __builtin_amdgcn_rcpf(fmaf(e0.w, f0.w, 1.f)), a00);
      a01 = fmaf(vw.w, __builtin_amdgcn_rcpf(fmaf(e0.w, f1.w, 1.f)), a01);
      a10 = fmaf(vw.w, __builtin_amdgcn_rcpf(fmaf(e1.w, f0.w, 1.f)), a10);
      a11 = fmaf(vw.w, __builtin_amdgcn_rcpf(fmaf(e1.w, f1.w, 1.f)), a11);
    }
  }

  sRed[0 * 512 + g * 64 + lane] = a00;
  sRed[1 * 512 + g * 64 + lane] = a01;
  sRed[2 * 512 + g * 64 + lane] = a10;
  sRed[3 * 512 + g * 64 + lane] = a11;
  __syncthreads();
  if (tid < 256) {
    int s = tid >> 4, t = tid & 15;
    int pp = (s >> 1) * 8 + (t >> 1);
    int sl = (s & 1) * 2 + (t & 1);
    float sum = 0.f;
    #pragma unroll
    for (int gg = 0; gg < 8; ++gg) sum += sRed[sl * 512 + gg * 64 + pp];
    out[((long)br * LL + (s0 + s)) * LL + (t0 + t)] = sWsum - 2.f * sum;
  }
}

extern "C" void kernel_launch(void* const* d_in, const int* in_sizes, int n_in,
                              void* d_out, int out_size, void* d_ws, size_t ws_size,
                              hipStream_t stream)
{
  const float* hidden  = (const float*)d_in[0];
  const float* W_src   = (const float*)d_in[1];
  const float* b_src   = (const float*)d_in[2];
  const float* W_tgt   = (const float*)d_in[3];
  const float* b_tgt   = (const float*)d_in[4];
  const float* w_out   = (const float*)d_in[5];
  const float* dense_W = (const float*)d_in[6];
  const float* dense_b = (const float*)d_in[7];
  const float* clf_W   = (const float*)d_in[8];
  const float* clf_b   = (const float*)d_in[9];
  float* out = (float*)d_out;
  char* ws = (char*)d_ws;

  unsigned short* Ab = (unsigned short*)ws;        // 256x768 bf16  [0, 384K)
  float* z  = (float*)(ws + 393216);               // 256x2304 f32
  float* Es = (float*)(ws + 2752512);              // 256x3072 f32
  float* Et = (float*)(ws + 5898240);              // 256x3072 f32

  hipLaunchKernelGGL(cvta_kernel, dim3(192), dim3(256), 0, stream,
      (const float4*)hidden, (uint2*)Ab);
  hipLaunchKernelGGL(gemm_kernel, dim3(512), dim3(256), 0, stream,
      Ab, W_src, W_tgt, dense_W, b_src, b_tgt, dense_b, out, z, Es, Et);
  hipLaunchKernelGGL(pair_kernel, dim3(8, 8, 9), dim3(512), 0, stream,
      Es, Et, w_out, z, clf_W, clf_b, out + OFF_REL);
}

// Round 11
// 44.630 us; speedup vs baseline: 1.9487x; 1.9487x over previous
//
#include <hip/hip_runtime.h>
#include <hip/hip_bf16.h>

#define LL 128
#define HH 768
#define OFF_REL  0
#define OFF_MASK 131072
#define OFF_HSRC 131840
#define OFF_HTGT 918272
#define SCALEC 2.8853900817779268f   // 2*log2(e):  e^{2x} = exp2(SCALEC*x)

typedef __attribute__((ext_vector_type(8))) short short8;
typedef __attribute__((ext_vector_type(4))) float floatx4;

__device__ inline unsigned short f2bf(float f) {
  unsigned u = __float_as_uint(f);
  u += 0x7FFFu + ((u >> 16) & 1u);
  return (unsigned short)(u >> 16);
}
struct us4 { unsigned short x, y, z, w; };

// ---------------- fp32 -> bf16: hidden + all three weights (53 MB traffic) ----------------
__global__ __launch_bounds__(256) void cvt_kernel(
    const float4* __restrict__ hs, const float4* __restrict__ wsrc,
    const float4* __restrict__ wtgt, const float4* __restrict__ wd,
    us4* __restrict__ ab, us4* __restrict__ wb)
{
  const int n0 = 49152;               // hidden: 196608/4
  const int n1 = n0 + 589824;         // W_src
  const int n2 = n1 + 589824;         // W_tgt
  const int n3 = n2 + 442368;         // dense_W
  int stride = gridDim.x * blockDim.x;
  for (int i = blockIdx.x * blockDim.x + threadIdx.x; i < n3; i += stride) {
    const float4* src; us4* dst;
    if (i < n0)      { src = hs   + i;        dst = ab + i; }
    else if (i < n1) { src = wsrc + (i - n0); dst = wb + (i - n0); }
    else if (i < n2) { src = wtgt + (i - n1); dst = wb + 589824 + (i - n1); }
    else             { src = wd   + (i - n2); dst = wb + 1179648 + (i - n2); }
    float4 v = *src;
    us4 o; o.x = f2bf(v.x); o.y = f2bf(v.y); o.z = f2bf(v.z); o.w = f2bf(v.w);
    *dst = o;
  }
}

// ---------------- bf16 GEMM: A[256x768] x Wb[8448x768]^T, 64x64 tile, LDS dbuf ----------------
// grid (132, 4) x 256 thr. 4 waves x 32x32 quadrants. BK=64, 2-phase, 1 barrier/iter.
__global__ __launch_bounds__(256, 4) void gemm_kernel(
    const unsigned short* __restrict__ Ab, const unsigned short* __restrict__ Wb,
    const float* __restrict__ b_src, const float* __restrict__ b_tgt,
    const float* __restrict__ dense_b,
    float* __restrict__ out, float* __restrict__ z,
    float* __restrict__ Es, float* __restrict__ Et)
{
  __shared__ unsigned short sA[2][64][72];   // 18.4 KB
  __shared__ unsigned short sB[2][64][72];   // 18.4 KB
  int tid = threadIdx.x;
  int wave = tid >> 6, lane = tid & 63;
  int nb = blockIdx.x, rb = blockIdx.y;
  int gcol0 = nb * 64;
  int grow0 = rb * 64;

  // staging roles: thread -> (row 0..31 [+32], 16B-slot 0..7 within 128B K-chunk)
  int s_row = tid >> 3, s_slot = (tid & 7) * 8;
  const unsigned short* gA0 = Ab + (long)(grow0 + s_row) * HH + s_slot;
  const unsigned short* gA1 = gA0 + 32 * HH;
  const unsigned short* gB0 = Wb + (long)(gcol0 + s_row) * HH + s_slot;
  const unsigned short* gB1 = gB0 + 32 * HH;

  // MFMA fragment roles
  int lr = lane & 15, lk8 = (lane >> 4) * 8;
  int wm = (wave >> 1) * 32, wn = (wave & 1) * 32;

  floatx4 acc[2][2];
  #pragma unroll
  for (int mi = 0; mi < 2; ++mi)
    #pragma unroll
    for (int ni = 0; ni < 2; ++ni)
      acc[mi][ni] = (floatx4){0.f, 0.f, 0.f, 0.f};

  // prologue: stage tile 0 into buf 0
  {
    uint4 a0 = *(const uint4*)(gA0);
    uint4 a1 = *(const uint4*)(gA1);
    uint4 b0 = *(const uint4*)(gB0);
    uint4 b1 = *(const uint4*)(gB1);
    *(uint4*)&sA[0][s_row][s_slot]      = a0;
    *(uint4*)&sA[0][s_row + 32][s_slot] = a1;
    *(uint4*)&sB[0][s_row][s_slot]      = b0;
    *(uint4*)&sB[0][s_row + 32][s_slot] = b1;
  }
  __syncthreads();

  #pragma unroll 2
  for (int kt = 0; kt < 12; ++kt) {
    int c = kt & 1;
    uint4 na0, na1, nb0, nb1;
    if (kt < 11) {
      int off = (kt + 1) * 64;
      na0 = *(const uint4*)(gA0 + off);
      na1 = *(const uint4*)(gA1 + off);
      nb0 = *(const uint4*)(gB0 + off);
      nb1 = *(const uint4*)(gB1 + off);
    }
    #pragma unroll
    for (int ks = 0; ks < 2; ++ks) {
      short8 fa0 = *(const short8*)&sA[c][wm + lr][ks * 32 + lk8];
      short8 fa1 = *(const short8*)&sA[c][wm + 16 + lr][ks * 32 + lk8];
      short8 fb0 = *(const short8*)&sB[c][wn + lr][ks * 32 + lk8];
      short8 fb1 = *(const short8*)&sB[c][wn + 16 + lr][ks * 32 + lk8];
      acc[0][0] = __builtin_amdgcn_mfma_f32_16x16x32_bf16(fa0, fb0, acc[0][0], 0, 0, 0);
      acc[0][1] = __builtin_amdgcn_mfma_f32_16x16x32_bf16(fa0, fb1, acc[0][1], 0, 0, 0);
      acc[1][0] = __builtin_amdgcn_mfma_f32_16x16x32_bf16(fa1, fb0, acc[1][0], 0, 0, 0);
      acc[1][1] = __builtin_amdgcn_mfma_f32_16x16x32_bf16(fa1, fb1, acc[1][1], 0, 0, 0);
    }
    if (kt < 11) {
      *(uint4*)&sA[c ^ 1][s_row][s_slot]      = na0;
      *(uint4*)&sA[c ^ 1][s_row + 32][s_slot] = na1;
      *(uint4*)&sB[c ^ 1][s_row][s_slot]      = nb0;
      *(uint4*)&sB[c ^ 1][s_row + 32][s_slot] = nb1;
    }
    __syncthreads();
  }

  // epilogue
  int lrow = (lane >> 4) * 4;
  #pragma unroll
  for (int mi = 0; mi < 2; ++mi)
  #pragma unroll
  for (int ni = 0; ni < 2; ++ni) {
    int colg = gcol0 + wn + ni * 16 + lr;
    int row0 = grow0 + wm + mi * 16 + lrow;
    if (nb < 48) {
      float bv = b_src[colg];
      #pragma unroll
      for (int r2 = 0; r2 < 4; ++r2) {
        int row = row0 + r2;
        float v = acc[mi][ni][r2] + bv;
        out[OFF_HSRC + row * 3072 + colg] = v;
        Es[row * 3072 + colg] = __builtin_amdgcn_exp2f(SCALEC * v);
      }
    } else if (nb < 96) {
      int cc = colg - 3072;
      float bv = b_tgt[cc];
      #pragma unroll
      for (int r2 = 0; r2 < 4; ++r2) {
        int row = row0 + r2;
        float v = acc[mi][ni][r2] + bv;
        out[OFF_HTGT + row * 3072 + cc] = v;
        Et[row * 3072 + cc] = __builtin_amdgcn_exp2f(SCALEC * v);
      }
    } else {
      int cc = colg - 6144;
      float bv = dense_b[cc];
      #pragma unroll
      for (int r2 = 0; r2 < 4; ++r2)
        z[(row0 + r2) * 2304 + cc] = acc[mi][ni][r2] + bv;
    }
  }
}

// ---------------- pairwise relation + token-mask head ----------------
// rel[b,r,s,t] = Wsum - 2*sum_h w[h] / (1 + Es[s,h]*Et[t,h])
#define PHC 256
__global__ __launch_bounds__(512) void pair_kernel(
    const float* __restrict__ Es, const float* __restrict__ Et,
    const float* __restrict__ w_out,
    const float* __restrict__ z, const float* __restrict__ clf_W,
    const float* __restrict__ clf_b, float* __restrict__ out)
{
  int tid = threadIdx.x;

  if (blockIdx.z == 8) {
    // token mask head
    int blk = blockIdx.y * 8 + blockIdx.x;
    int wave = tid >> 6, lane = tid & 63;
    int slot = blk * 8 + wave;
    for (int o = slot; o < 768; o += 512) {
      int b = o / 384, rem = o - b * 384;
      int t = rem >> 7, lt = rem & 127;
      const float* zr = z + (long)(b * LL + lt) * 2304 + t * HH;
      float acc = 0.f;
      for (int h = lane; h < HH; h += 64) {
        float x = zr[h];
        float th = 1.f - 2.f * __builtin_amdgcn_rcpf(1.f + __builtin_amdgcn_exp2f(SCALEC * x));
        acc = fmaf(clf_W[h], th, acc);
      }
      #pragma unroll
      for (int d = 32; d; d >>= 1) acc += __shfl_down(acc, d);
      if (lane == 0) out[OFF_MASK + o] = acc + clf_b[0];
    }
    return;
  }

  __shared__ float sA[16][PHC + 4];
  __shared__ float sB[16][PHC + 4];
  __shared__ float sRed[2048];       // [k][g][p]
  __shared__ float sWsum;

  int g = tid >> 6, lane = tid & 63;
  int sq = lane >> 3, tq = lane & 7;
  int t0 = blockIdx.x * 16, s0 = blockIdx.y * 16;
  int br = blockIdx.z, bb = br >> 2, r = br & 3;

  if (tid < 64) {
    float wsm = 0.f;
    for (int h = tid; h < HH; h += 64) wsm += w_out[h];
    #pragma unroll
    for (int d = 32; d; d >>= 1) wsm += __shfl_down(wsm, d);
    if (tid == 0) sWsum = wsm;
  }

  float a00 = 0.f, a01 = 0.f, a10 = 0.f, a11 = 0.f;

  for (int c = 0; c < HH; c += PHC) {
    int offu = __builtin_amdgcn_readfirstlane(c + g * 32);
    float4 wv[8];
    #pragma unroll
    for (int q = 0; q < 8; ++q) wv[q] = *(const float4*)(w_out + offu + q * 4);

    __syncthreads();
    #pragma unroll
    for (int j = 0; j < 2; ++j) {
      int idx = tid * 2 + j;
      int row = idx >> 6, col4 = (idx & 63) * 4;
      *(float4*)&sA[row][col4] =
          *(const float4*)(Es + (long)(bb * LL + s0 + row) * 3072 + r * HH + c + col4);
      *(float4*)&sB[row][col4] =
          *(const float4*)(Et + (long)(bb * LL + t0 + row) * 3072 + r * HH + c + col4);
    }
    __syncthreads();

    const float* pA0 = &sA[2 * sq][g * 32];
    const float* pA1 = &sA[2 * sq + 1][g * 32];
    const float* pB0 = &sB[2 * tq][g * 32];
    const float* pB1 = &sB[2 * tq + 1][g * 32];
    #pragma unroll
    for (int hh = 0; hh < 32; hh += 4) {
      float4 e0 = *(const float4*)(pA0 + hh);
      float4 e1 = *(const float4*)(pA1 + hh);
      float4 f0 = *(const float4*)(pB0 + hh);
      float4 f1 = *(const float4*)(pB1 + hh);
      float4 vw = wv[hh >> 2];
      a00 = fmaf(vw.x, __builtin_amdgcn_rcpf(fmaf(e0.x, f0.x, 1.f)), a00);
      a01 = fmaf(vw.x, __builtin_amdgcn_rcpf(fmaf(e0.x, f1.x, 1.f)), a01);
      a10 = fmaf(vw.x, __builtin_amdgcn_rcpf(fmaf(e1.x, f0.x, 1.f)), a10);
      a11 = fmaf(vw.x, __builtin_amdgcn_rcpf(fmaf(e1.x, f1.x, 1.f)), a11);
      a00 = fmaf(vw.y, __builtin_amdgcn_rcpf(fmaf(e0.y, f0.y, 1.f)), a00);
      a01 = fmaf(vw.y, __builtin_amdgcn_rcpf(fmaf(e0.y, f1.y, 1.f)), a01);
      a10 = fmaf(vw.y, __builtin_amdgcn_rcpf(fmaf(e1.y, f0.y, 1.f)), a10);
      a11 = fmaf(vw.y, __builtin_amdgcn_rcpf(fmaf(e1.y, f1.y, 1.f)), a11);
      a00 = fmaf(vw.z, __builtin_amdgcn_rcpf(fmaf(e0.z, f0.z, 1.f)), a00);
      a01 = fmaf(vw.z, __builtin_amdgcn_rcpf(fmaf(e0.z, f1.z, 1.f)), a01);
      a10 = fmaf(vw.z, __builtin_amdgcn_rcpf(fmaf(e1.z, f0.z, 1.f)), a10);
      a11 = fmaf(vw.z, __builtin_amdgcn_rcpf(fmaf(e1.z, f1.z, 1.f)), a11);
      a00 = fmaf(vw.w, __builtin_amdgcn_rcpf(fmaf(e0.w, f0.w, 1.f)), a00);
      a01 = fmaf(vw.w, __builtin_amdgcn_rcpf(fmaf(e0.w, f1.w, 1.f)), a01);
      a10 = fmaf(vw.w, __builtin_amdgcn_rcpf(fmaf(e1.w, f0.w, 1.f)), a10);
      a11 = fmaf(vw.w, __builtin_amdgcn_rcpf(fmaf(e1.w, f1.w, 1.f)), a11);
    }
  }

  sRed[0 * 512 + g * 64 + lane] = a00;
  sRed[1 * 512 + g * 64 + lane] = a01;
  sRed[2 * 512 + g * 64 + lane] = a10;
  sRed[3 * 512 + g * 64 + lane] = a11;
  __syncthreads();
  if (tid < 256) {
    int s = tid >> 4, t = tid & 15;
    int pp = (s >> 1) * 8 + (t >> 1);
    int sl = (s & 1) * 2 + (t & 1);
    float sum = 0.f;
    #pragma unroll
    for (int gg = 0; gg < 8; ++gg) sum += sRed[sl * 512 + gg * 64 + pp];
    out[((long)br * LL + (s0 + s)) * LL + (t0 + t)] = sWsum - 2.f * sum;
  }
}

extern "C" void kernel_launch(void* const* d_in, const int* in_sizes, int n_in,
                              void* d_out, int out_size, void* d_ws, size_t ws_size,
                              hipStream_t stream)
{
  const float* hidden  = (const float*)d_in[0];
  const float* W_src   = (const float*)d_in[1];
  const float* b_src   = (const float*)d_in[2];
  const float* W_tgt   = (const float*)d_in[3];
  const float* b_tgt   = (const float*)d_in[4];
  const float* w_out   = (const float*)d_in[5];
  const float* dense_W = (const float*)d_in[6];
  const float* dense_b = (const float*)d_in[7];
  const float* clf_W   = (const float*)d_in[8];
  const float* clf_b   = (const float*)d_in[9];
  float* out = (float*)d_out;
  char* ws = (char*)d_ws;

  unsigned short* Ab = (unsigned short*)ws;            // 256x768 bf16   [0, 384K)
  unsigned short* Wb = (unsigned short*)(ws + 393216); // 8448x768 bf16  [384K, ~13.4M)
  float* z  = (float*)(ws + 13369344);                 // 256x2304 f32
  float* Es = (float*)(ws + 15728640);                 // 256x3072 f32
  float* Et = (float*)(ws + 18874368);                 // 256x3072 f32

  hipLaunchKernelGGL(cvt_kernel, dim3(2048), dim3(256), 0, stream,
      (const float4*)hidden, (const float4*)W_src, (const float4*)W_tgt,
      (const float4*)dense_W, (us4*)Ab, (us4*)Wb);
  hipLaunchKernelGGL(gemm_kernel, dim3(132, 4), dim3(256), 0, stream,
      Ab, Wb, b_src, b_tgt, dense_b, out, z, Es, Et);
  hipLaunchKernelGGL(pair_kernel, dim3(8, 8, 9), dim3(512), 0, stream,
      Es, Et, w_out, z, clf_W, clf_b, out + OFF_REL);
}

// Round 12
// 44.394 us; speedup vs baseline: 1.9591x; 1.0053x over previous
//
#include <hip/hip_runtime.h>
#include <hip/hip_bf16.h>

#define LL 128
#define HH 768
#define OFF_REL  0
#define OFF_MASK 131072
#define OFF_HSRC 131840
#define OFF_HTGT 918272
#define SCALEC 2.8853900817779268f   // 2*log2(e):  e^{2x} = exp2(SCALEC*x)

typedef __attribute__((ext_vector_type(8))) short short8;
typedef __attribute__((ext_vector_type(4))) float floatx4;

__device__ __forceinline__ uint4 cvt8(float4 lo, float4 hi) {
  union { __hip_bfloat162 h2[4]; uint4 u4; } u;
  u.h2[0] = __float22bfloat162_rn(float2{lo.x, lo.y});
  u.h2[1] = __float22bfloat162_rn(float2{lo.z, lo.w});
  u.h2[2] = __float22bfloat162_rn(float2{hi.x, hi.y});
  u.h2[3] = __float22bfloat162_rn(float2{hi.z, hi.w});
  return u.u4;
}

// ---------------- fused cvt+GEMM: hidden[256x768]f32 x W[8448x768]^T f32 ----------------
// grid (132, 4) x 256 thr. 64x64 tile, 4 waves x 32x32 quadrants. BK=64, LDS dbuf,
// 1 barrier/iter. Staging: 8x float4 fp32 loads -> cvt_pk -> ds_write_b128 (bf16).
__global__ __launch_bounds__(256, 4) void gemm_kernel(
    const float* __restrict__ hidden,
    const float* __restrict__ Wsrc, const float* __restrict__ Wtgt,
    const float* __restrict__ Wd,
    const float* __restrict__ b_src, const float* __restrict__ b_tgt,
    const float* __restrict__ dense_b,
    float* __restrict__ out, float* __restrict__ z,
    float* __restrict__ Es, float* __restrict__ Et)
{
  __shared__ unsigned short sA[2][64][72];   // 18.4 KB
  __shared__ unsigned short sB[2][64][72];   // 18.4 KB
  int tid = threadIdx.x;
  int wave = tid >> 6, lane = tid & 63;
  int nb = blockIdx.x, rb = blockIdx.y;
  int gcol0 = nb * 64;
  int grow0 = rb * 64;

  const float* W; int wrow0; int which;
  if (nb < 48)      { W = Wsrc; wrow0 = gcol0;        which = 0; }
  else if (nb < 96) { W = Wtgt; wrow0 = gcol0 - 3072; which = 1; }
  else              { W = Wd;   wrow0 = gcol0 - 6144; which = 2; }

  // staging roles: thread -> (row 0..31 [+32], 8-float slot 0..7 within 64-k chunk)
  int s_row = tid >> 3, s_slot = (tid & 7) * 8;
  const float* gA0 = hidden + (long)(grow0 + s_row) * HH + s_slot;
  const float* gA1 = gA0 + 32 * HH;
  const float* gB0 = W + (long)(wrow0 + s_row) * HH + s_slot;
  const float* gB1 = gB0 + 32 * HH;

  // MFMA fragment roles
  int lr = lane & 15, lk8 = (lane >> 4) * 8;
  int wm = (wave >> 1) * 32, wn = (wave & 1) * 32;

  floatx4 acc[2][2];
  #pragma unroll
  for (int mi = 0; mi < 2; ++mi)
    #pragma unroll
    for (int ni = 0; ni < 2; ++ni)
      acc[mi][ni] = (floatx4){0.f, 0.f, 0.f, 0.f};

  // prologue: stage tile 0 into buf 0
  {
    float4 a0l = *(const float4*)(gA0),     a0h = *(const float4*)(gA0 + 4);
    float4 a1l = *(const float4*)(gA1),     a1h = *(const float4*)(gA1 + 4);
    float4 b0l = *(const float4*)(gB0),     b0h = *(const float4*)(gB0 + 4);
    float4 b1l = *(const float4*)(gB1),     b1h = *(const float4*)(gB1 + 4);
    *(uint4*)&sA[0][s_row][s_slot]      = cvt8(a0l, a0h);
    *(uint4*)&sA[0][s_row + 32][s_slot] = cvt8(a1l, a1h);
    *(uint4*)&sB[0][s_row][s_slot]      = cvt8(b0l, b0h);
    *(uint4*)&sB[0][s_row + 32][s_slot] = cvt8(b1l, b1h);
  }
  __syncthreads();

  #pragma unroll 2
  for (int kt = 0; kt < 12; ++kt) {
    int c = kt & 1;
    float4 na0l, na0h, na1l, na1h, nb0l, nb0h, nb1l, nb1h;
    if (kt < 11) {
      int off = (kt + 1) * 64;
      na0l = *(const float4*)(gA0 + off); na0h = *(const float4*)(gA0 + off + 4);
      na1l = *(const float4*)(gA1 + off); na1h = *(const float4*)(gA1 + off + 4);
      nb0l = *(const float4*)(gB0 + off); nb0h = *(const float4*)(gB0 + off + 4);
      nb1l = *(const float4*)(gB1 + off); nb1h = *(const float4*)(gB1 + off + 4);
    }
    #pragma unroll
    for (int ks = 0; ks < 2; ++ks) {
      short8 fa0 = *(const short8*)&sA[c][wm + lr][ks * 32 + lk8];
      short8 fa1 = *(const short8*)&sA[c][wm + 16 + lr][ks * 32 + lk8];
      short8 fb0 = *(const short8*)&sB[c][wn + lr][ks * 32 + lk8];
      short8 fb1 = *(const short8*)&sB[c][wn + 16 + lr][ks * 32 + lk8];
      acc[0][0] = __builtin_amdgcn_mfma_f32_16x16x32_bf16(fa0, fb0, acc[0][0], 0, 0, 0);
      acc[0][1] = __builtin_amdgcn_mfma_f32_16x16x32_bf16(fa0, fb1, acc[0][1], 0, 0, 0);
      acc[1][0] = __builtin_amdgcn_mfma_f32_16x16x32_bf16(fa1, fb0, acc[1][0], 0, 0, 0);
      acc[1][1] = __builtin_amdgcn_mfma_f32_16x16x32_bf16(fa1, fb1, acc[1][1], 0, 0, 0);
    }
    if (kt < 11) {
      *(uint4*)&sA[c ^ 1][s_row][s_slot]      = cvt8(na0l, na0h);
      *(uint4*)&sA[c ^ 1][s_row + 32][s_slot] = cvt8(na1l, na1h);
      *(uint4*)&sB[c ^ 1][s_row][s_slot]      = cvt8(nb0l, nb0h);
      *(uint4*)&sB[c ^ 1][s_row + 32][s_slot] = cvt8(nb1l, nb1h);
    }
    __syncthreads();
  }

  // epilogue
  int lrow = (lane >> 4) * 4;
  #pragma unroll
  for (int mi = 0; mi < 2; ++mi)
  #pragma unroll
  for (int ni = 0; ni < 2; ++ni) {
    int colg = gcol0 + wn + ni * 16 + lr;
    int row0 = grow0 + wm + mi * 16 + lrow;
    if (which == 0) {
      float bv = b_src[colg];
      #pragma unroll
      for (int r2 = 0; r2 < 4; ++r2) {
        int row = row0 + r2;
        float v = acc[mi][ni][r2] + bv;
        out[OFF_HSRC + row * 3072 + colg] = v;
        Es[row * 3072 + colg] = __builtin_amdgcn_exp2f(SCALEC * v);
      }
    } else if (which == 1) {
      int cc = colg - 3072;
      float bv = b_tgt[cc];
      #pragma unroll
      for (int r2 = 0; r2 < 4; ++r2) {
        int row = row0 + r2;
        float v = acc[mi][ni][r2] + bv;
        out[OFF_HTGT + row * 3072 + cc] = v;
        Et[row * 3072 + cc] = __builtin_amdgcn_exp2f(SCALEC * v);
      }
    } else {
      int cc = colg - 6144;
      float bv = dense_b[cc];
      #pragma unroll
      for (int r2 = 0; r2 < 4; ++r2)
        z[(row0 + r2) * 2304 + cc] = acc[mi][ni][r2] + bv;
    }
  }
}

// ---------------- pairwise relation + token-mask head ----------------
// rel[b,r,s,t] = Wsum - 2*sum_h w[h] / (1 + Es[s,h]*Et[t,h])
#define PHC 256
__global__ __launch_bounds__(512) void pair_kernel(
    const float* __restrict__ Es, const float* __restrict__ Et,
    const float* __restrict__ w_out,
    const float* __restrict__ z, const float* __restrict__ clf_W,
    const float* __restrict__ clf_b, float* __restrict__ out)
{
  int tid = threadIdx.x;

  if (blockIdx.z == 8) {
    // token mask head
    int blk = blockIdx.y * 8 + blockIdx.x;
    int wave = tid >> 6, lane = tid & 63;
    int slot = blk * 8 + wave;
    for (int o = slot; o < 768; o += 512) {
      int b = o / 384, rem = o - b * 384;
      int t = rem >> 7, lt = rem & 127;
      const float* zr = z + (long)(b * LL + lt) * 2304 + t * HH;
      float acc = 0.f;
      for (int h = lane; h < HH; h += 64) {
        float x = zr[h];
        float th = 1.f - 2.f * __builtin_amdgcn_rcpf(1.f + __builtin_amdgcn_exp2f(SCALEC * x));
        acc = fmaf(clf_W[h], th, acc);
      }
      #pragma unroll
      for (int d = 32; d; d >>= 1) acc += __shfl_down(acc, d);
      if (lane == 0) out[OFF_MASK + o] = acc + clf_b[0];
    }
    return;
  }

  __shared__ float sA[16][PHC + 4];
  __shared__ float sB[16][PHC + 4];
  __shared__ float sRed[2048];       // [k][g][p]
  __shared__ float sWsum;

  int g = tid >> 6, lane = tid & 63;
  int sq = lane >> 3, tq = lane & 7;
  int t0 = blockIdx.x * 16, s0 = blockIdx.y * 16;
  int br = blockIdx.z, bb = br >> 2, r = br & 3;

  if (tid < 64) {
    float wsm = 0.f;
    for (int h = tid; h < HH; h += 64) wsm += w_out[h];
    #pragma unroll
    for (int d = 32; d; d >>= 1) wsm += __shfl_down(wsm, d);
    if (tid == 0) sWsum = wsm;
  }

  float a00 = 0.f, a01 = 0.f, a10 = 0.f, a11 = 0.f;

  for (int c = 0; c < HH; c += PHC) {
    int offu = __builtin_amdgcn_readfirstlane(c + g * 32);
    float4 wv[8];
    #pragma unroll
    for (int q = 0; q < 8; ++q) wv[q] = *(const float4*)(w_out + offu + q * 4);

    __syncthreads();
    #pragma unroll
    for (int j = 0; j < 2; ++j) {
      int idx = tid * 2 + j;
      int row = idx >> 6, col4 = (idx & 63) * 4;
      *(float4*)&sA[row][col4] =
          *(const float4*)(Es + (long)(bb * LL + s0 + row) * 3072 + r * HH + c + col4);
      *(float4*)&sB[row][col4] =
          *(const float4*)(Et + (long)(bb * LL + t0 + row) * 3072 + r * HH + c + col4);
    }
    __syncthreads();

    const float* pA0 = &sA[2 * sq][g * 32];
    const float* pA1 = &sA[2 * sq + 1][g * 32];
    const float* pB0 = &sB[2 * tq][g * 32];
    const float* pB1 = &sB[2 * tq + 1][g * 32];
    #pragma unroll
    for (int hh = 0; hh < 32; hh += 4) {
      float4 e0 = *(const float4*)(pA0 + hh);
      float4 e1 = *(const float4*)(pA1 + hh);
      float4 f0 = *(const float4*)(pB0 + hh);
      float4 f1 = *(const float4*)(pB1 + hh);
      float4 vw = wv[hh >> 2];
      a00 = fmaf(vw.x, __builtin_amdgcn_rcpf(fmaf(e0.x, f0.x, 1.f)), a00);
      a01 = fmaf(vw.x, __builtin_amdgcn_rcpf(fmaf(e0.x, f1.x, 1.f)), a01);
      a10 = fmaf(vw.x, __builtin_amdgcn_rcpf(fmaf(e1.x, f0.x, 1.f)), a10);
      a11 = fmaf(vw.x, __builtin_amdgcn_rcpf(fmaf(e1.x, f1.x, 1.f)), a11);
      a00 = fmaf(vw.y, __builtin_amdgcn_rcpf(fmaf(e0.y, f0.y, 1.f)), a00);
      a01 = fmaf(vw.y, __builtin_amdgcn_rcpf(fmaf(e0.y, f1.y, 1.f)), a01);
      a10 = fmaf(vw.y, __builtin_amdgcn_rcpf(fmaf(e1.y, f0.y, 1.f)), a10);
      a11 = fmaf(vw.y, __builtin_amdgcn_rcpf(fmaf(e1.y, f1.y, 1.f)), a11);
      a00 = fmaf(vw.z, __builtin_amdgcn_rcpf(fmaf(e0.z, f0.z, 1.f)), a00);
      a01 = fmaf(vw.z, __builtin_amdgcn_rcpf(fmaf(e0.z, f1.z, 1.f)), a01);
      a10 = fmaf(vw.z, __builtin_amdgcn_rcpf(fmaf(e1.z, f0.z, 1.f)), a10);
      a11 = fmaf(vw.z, __builtin_amdgcn_rcpf(fmaf(e1.z, f1.z, 1.f)), a11);
      a00 = fmaf(vw.w, __builtin_amdgcn_rcpf(fmaf(e0.w, f0.w, 1.f)), a00);
      a01 = fmaf(vw.w, __builtin_amdgcn_rcpf(fmaf(e0.w, f1.w, 1.f)), a01);
      a10 = fmaf(vw.w, __builtin_amdgcn_rcpf(fmaf(e1.w, f0.w, 1.f)), a10);
      a11 = fmaf(vw.w, __builtin_amdgcn_rcpf(fmaf(e1.w, f1.w, 1.f)), a11);
    }
  }

  sRed[0 * 512 + g * 64 + lane] = a00;
  sRed[1 * 512 + g * 64 + lane] = a01;
  sRed[2 * 512 + g * 64 + lane] = a10;
  sRed[3 * 512 + g * 64 + lane] = a11;
  __syncthreads();
  if (tid < 256) {
    int s = tid >> 4, t = tid & 15;
    int pp = (s >> 1) * 8 + (t >> 1);
    int sl = (s & 1) * 2 + (t & 1);
    float sum = 0.f;
    #pragma unroll
    for (int gg = 0; gg < 8; ++gg) sum += sRed[sl * 512 + gg * 64 + pp];
    out[((long)br * LL + (s0 + s)) * LL + (t0 + t)] = sWsum - 2.f * sum;
  }
}

extern "C" void kernel_launch(void* const* d_in, const int* in_sizes, int n_in,
                              void* d_out, int out_size, void* d_ws, size_t ws_size,
                              hipStream_t stream)
{
  const float* hidden  = (const float*)d_in[0];
  const float* W_src   = (const float*)d_in[1];
  const float* b_src   = (const float*)d_in[2];
  const float* W_tgt   = (const float*)d_in[3];
  const float* b_tgt   = (const float*)d_in[4];
  const float* w_out   = (const float*)d_in[5];
  const float* dense_W = (const float*)d_in[6];
  const float* dense_b = (const float*)d_in[7];
  const float* clf_W   = (const float*)d_in[8];
  const float* clf_b   = (const float*)d_in[9];
  float* out = (float*)d_out;
  char* ws = (char*)d_ws;

  float* z  = (float*)(ws);                        // 256x2304 f32
  float* Es = (float*)(ws + 2359296);              // 256x3072 f32
  float* Et = (float*)(ws + 5505024);              // 256x3072 f32

  hipLaunchKernelGGL(gemm_kernel, dim3(132, 4), dim3(256), 0, stream,
      hidden, W_src, W_tgt, dense_W, b_src, b_tgt, dense_b, out, z, Es, Et);
  hipLaunchKernelGGL(pair_kernel, dim3(8, 8, 9), dim3(512), 0, stream,
      Es, Et, w_out, z, clf_W, clf_b, out + OFF_REL);
}